// Round 8
// baseline (161.606 us; speedup 1.0000x reference)
//
#include <hip/hip_runtime.h>
#include <math.h>

// Problem constants (B=64, J=17, H=W=128)
#define BJ    1088               // B*J maps per tensor
#define NMAP  (2 * BJ)           // 2176 maps (pred then gt)
#define HW    16384              // 128*128
#define NTH   512                // 8 waves per block
#define NWAVE (NTH / 64)
#define LDSF4 3072               // float4s staged in LDS (48 KB) -> 3 blocks/CU
#define K_LDS 6                  // LDS float4 slots per thread (3072/512)
#define K_REG 2                  // register float4 per thread (last 16 KB of map)

typedef __attribute__((address_space(3))) unsigned int       lds_u32;
typedef __attribute__((address_space(1))) const unsigned int glb_u32;

// Monotonic unsigned key for float bits: orders like float compare.
__device__ __forceinline__ unsigned int ford(unsigned int u) {
    return (u & 0x80000000u) ? ~u : (u | 0x80000000u);
}
__device__ __forceinline__ unsigned int ford_inv(unsigned int o) {
    return (o & 0x80000000u) ? (o & 0x7fffffffu) : ~o;
}

// One 512-thread block per map, 48 KB LDS -> 3 blocks/CU (24 waves, 75% cap;
// R7's 64 KB capped at 2 blocks/27% occ — more resident streams is the one
// lever that tracked with speed across R1-R7). Staging uses async
// global_load_lds width=16 (no VGPR round-trip, no staging VALU); the last
// quarter of the map lives in 8 VGPRs/thread and is scanned while the LDS
// loads are in flight. One HBM sweep total; sweep 2 from LDS + registers.
__global__ __launch_bounds__(NTH, 6) void hm_stats(const float* __restrict__ outp,
                                                   const float* __restrict__ tgtp,
                                                   float* __restrict__ d)
{
    __shared__ float hm[LDSF4 * 4];                // 48 KB, global order [0, 12288)
    __shared__ unsigned long long rk[NWAVE];
    __shared__ float rs[NWAVE], rc[NWAVE];

    const int m = blockIdx.x;                      // [0, NMAP)
    const int t = threadIdx.x;
    const int wv = t >> 6, ln = t & 63;
    const float* __restrict__ src = (m < BJ)
        ? (outp + (size_t)m * HW)
        : (tgtp + (size_t)(m - BJ) * HW);
    const float4* __restrict__ s4 = (const float4*)src;
    float4* hm4 = (float4*)hm;

    // ---- issue register loads FIRST (so their waitcnt doesn't drain the
    // lds-load queue), then the async global->LDS burst for this wave's slices
    float4 r[K_REG];
#pragma unroll
    for (int k = 0; k < K_REG; ++k) r[k] = s4[LDSF4 + t + k * NTH];

#pragma unroll
    for (int k = 0; k < K_LDS; ++k) {
        const int slice = wv * K_LDS + k;          // [0, 48) wave-uniform
        __builtin_amdgcn_global_load_lds((glb_u32*)(s4 + (slice << 6) + ln),
                                         (lds_u32*)(hm4 + (slice << 6)),
                                         16, 0, 0);
    }

    // ---- scan register part while LDS loads are in flight (chains 4..7;
    // per-chain idx monotone increasing -> '>' keeps first occurrence)
    float mx4 = -INFINITY, mx5 = -INFINITY, mx6 = -INFINITY, mx7 = -INFINITY;
    int   ix4 = 0, ix5 = 0, ix6 = 0, ix7 = 0;
#pragma unroll
    for (int k = 0; k < K_REG; ++k) {
        const int base = (LDSF4 + t + k * NTH) << 2;
        if (r[k].x > mx4) { mx4 = r[k].x; ix4 = base;     }
        if (r[k].y > mx5) { mx5 = r[k].y; ix5 = base + 1; }
        if (r[k].z > mx6) { mx6 = r[k].z; ix6 = base + 2; }
        if (r[k].w > mx7) { mx7 = r[k].w; ix7 = base + 3; }
    }

    __syncthreads();                               // drains vmcnt(0): LDS part ready

    // ---- scan LDS part (chains 0..3), contiguous-f4-per-lane = conflict-free
    float mx0 = -INFINITY, mx1 = -INFINITY, mx2 = -INFINITY, mx3 = -INFINITY;
    int   ix0 = 0, ix1 = 0, ix2 = 0, ix3 = 0;
#pragma unroll
    for (int k = 0; k < K_LDS; ++k) {
        const float4 v = hm4[t + k * NTH];
        const int base = (t + k * NTH) << 2;
        if (v.x > mx0) { mx0 = v.x; ix0 = base;     }
        if (v.y > mx1) { mx1 = v.y; ix1 = base + 1; }
        if (v.z > mx2) { mx2 = v.z; ix2 = base + 2; }
        if (v.w > mx3) { mx3 = v.w; ix3 = base + 3; }
    }

    // merge 8 chains via u64 keys: (ord(val)<<32)|~idx — max = (max val, min idx)
    unsigned long long key;
    {
        unsigned long long k0 = ((unsigned long long)ford(__float_as_uint(mx0)) << 32) | (unsigned int)~ix0;
        unsigned long long k1 = ((unsigned long long)ford(__float_as_uint(mx1)) << 32) | (unsigned int)~ix1;
        unsigned long long k2 = ((unsigned long long)ford(__float_as_uint(mx2)) << 32) | (unsigned int)~ix2;
        unsigned long long k3 = ((unsigned long long)ford(__float_as_uint(mx3)) << 32) | (unsigned int)~ix3;
        unsigned long long k4 = ((unsigned long long)ford(__float_as_uint(mx4)) << 32) | (unsigned int)~ix4;
        unsigned long long k5 = ((unsigned long long)ford(__float_as_uint(mx5)) << 32) | (unsigned int)~ix5;
        unsigned long long k6 = ((unsigned long long)ford(__float_as_uint(mx6)) << 32) | (unsigned int)~ix6;
        unsigned long long k7 = ((unsigned long long)ford(__float_as_uint(mx7)) << 32) | (unsigned int)~ix7;
        unsigned long long a = k0 > k1 ? k0 : k1;
        unsigned long long b = k2 > k3 ? k2 : k3;
        unsigned long long c = k4 > k5 ? k4 : k5;
        unsigned long long e = k6 > k7 ? k6 : k7;
        a = b > a ? b : a;  c = e > c ? e : c;
        key = c > a ? c : a;
    }
#pragma unroll
    for (int off = 32; off >= 1; off >>= 1) {
        const unsigned long long ok = __shfl_xor(key, off, 64);
        key = (ok > key) ? ok : key;
    }
    if (ln == 0) rk[wv] = key;
    __syncthreads();
    unsigned long long bkey = rk[0];
#pragma unroll
    for (int w = 1; w < NWAVE; ++w) bkey = (rk[w] > bkey) ? rk[w] : bkey;

    const float maxv = __uint_as_float(ford_inv((unsigned int)(bkey >> 32)));
    const int   midx = (int)~(unsigned int)(bkey & 0xffffffffu);
    const float ym  = (float)(midx >> 7);          // reference: idx // H (H=128 stride)
    const float xm  = (float)(midx & 127);
    const float thv = maxv * 0.5f;

    // ---- sweep 2: masked distance sum (LDS part + register part)
    float s = 0.0f, c = 0.0f;
#pragma unroll
    for (int k = 0; k < K_LDS; ++k) {
        const float4 v = hm4[t + k * NTH];
        const int g4 = t + k * NTH;
        const float dy  = (float)(g4 >> 5) - ym;   // all 4 elems share a row
        const float dy2 = dy * dy;
        const float cb  = (float)((g4 << 2) & 127) - xm;
        {
            const float dx = cb;        const float ds = __builtin_amdgcn_sqrtf(fmaf(dx, dx, dy2));
            const float mk = (v.x > thv) ? 1.0f : 0.0f;  s = fmaf(mk, ds, s);  c += mk;
        }
        {
            const float dx = cb + 1.0f; const float ds = __builtin_amdgcn_sqrtf(fmaf(dx, dx, dy2));
            const float mk = (v.y > thv) ? 1.0f : 0.0f;  s = fmaf(mk, ds, s);  c += mk;
        }
        {
            const float dx = cb + 2.0f; const float ds = __builtin_amdgcn_sqrtf(fmaf(dx, dx, dy2));
            const float mk = (v.z > thv) ? 1.0f : 0.0f;  s = fmaf(mk, ds, s);  c += mk;
        }
        {
            const float dx = cb + 3.0f; const float ds = __builtin_amdgcn_sqrtf(fmaf(dx, dx, dy2));
            const float mk = (v.w > thv) ? 1.0f : 0.0f;  s = fmaf(mk, ds, s);  c += mk;
        }
    }
#pragma unroll
    for (int k = 0; k < K_REG; ++k) {
        const int g4 = LDSF4 + t + k * NTH;
        const float dy  = (float)(g4 >> 5) - ym;
        const float dy2 = dy * dy;
        const float cb  = (float)((g4 << 2) & 127) - xm;
        {
            const float dx = cb;        const float ds = __builtin_amdgcn_sqrtf(fmaf(dx, dx, dy2));
            const float mk = (r[k].x > thv) ? 1.0f : 0.0f;  s = fmaf(mk, ds, s);  c += mk;
        }
        {
            const float dx = cb + 1.0f; const float ds = __builtin_amdgcn_sqrtf(fmaf(dx, dx, dy2));
            const float mk = (r[k].y > thv) ? 1.0f : 0.0f;  s = fmaf(mk, ds, s);  c += mk;
        }
        {
            const float dx = cb + 2.0f; const float ds = __builtin_amdgcn_sqrtf(fmaf(dx, dx, dy2));
            const float mk = (r[k].z > thv) ? 1.0f : 0.0f;  s = fmaf(mk, ds, s);  c += mk;
        }
        {
            const float dx = cb + 3.0f; const float ds = __builtin_amdgcn_sqrtf(fmaf(dx, dx, dy2));
            const float mk = (r[k].w > thv) ? 1.0f : 0.0f;  s = fmaf(mk, ds, s);  c += mk;
        }
    }

#pragma unroll
    for (int off = 32; off >= 1; off >>= 1) {
        s += __shfl_xor(s, off, 64);
        c += __shfl_xor(c, off, 64);
    }
    if (ln == 0) { rs[wv] = s; rc[wv] = c; }
    __syncthreads();
    if (t == 0) {
#pragma unroll
        for (int w = 1; w < NWAVE; ++w) { s += rs[w]; c += rc[w]; }
        const float mean = s / fmaxf(c, 1.0f);
        const float dd   = (c > 0.0f) ? (mean / 181.02f) : 1.0f;   // MAX_DIST
        d[m] = (maxv > 0.0f) ? dd : 0.0f;
    }
}

// Single-block final reduction: sum |gt - pred| / J / B
__global__ __launch_bounds__(256) void finalize(const float* __restrict__ d,
                                                float* __restrict__ out)
{
    __shared__ float rs[4];
    const int t = threadIdx.x;
    float acc = 0.0f;
    for (int i = t; i < BJ; i += 256)
        acc += fabsf(d[BJ + i] - d[i]);
#pragma unroll
    for (int off = 32; off >= 1; off >>= 1)
        acc += __shfl_down(acc, off, 64);
    const int wave = t >> 6, lane = t & 63;
    if (lane == 0) rs[wave] = acc;
    __syncthreads();
    if (t == 0) {
        acc = rs[0] + rs[1] + rs[2] + rs[3];
        out[0] = acc / 17.0f / 64.0f;              // / J / B, reference order
    }
}

extern "C" void kernel_launch(void* const* d_in, const int* in_sizes, int n_in,
                              void* d_out, int out_size, void* d_ws, size_t ws_size,
                              hipStream_t stream) {
    const float* outp = (const float*)d_in[0];     // [64,17,128,128] f32
    const float* tgtp = (const float*)d_in[1];
    float* d = (float*)d_ws;                       // NMAP floats

    hm_stats<<<dim3(NMAP), dim3(NTH), 0, stream>>>(outp, tgtp, d);
    finalize<<<dim3(1),    dim3(256), 0, stream>>>(d, (float*)d_out);
}

// Round 9
// 155.349 us; speedup vs baseline: 1.0403x; 1.0403x over previous
//
#include <hip/hip_runtime.h>
#include <math.h>

// Problem constants (B=64, J=17, H=W=128)
#define BJ    1088               // B*J maps per tensor
#define NMAP  (2 * BJ)           // 2176 maps (pred then gt)
#define HW    16384              // 128*128
#define NTH   512                // 8 waves per block
#define NWAVE (NTH / 64)
#define F4PT  (HW / 4 / NTH)     // 8 float4 per thread

// Monotonic unsigned key for float bits: orders like float compare.
__device__ __forceinline__ unsigned int ford(unsigned int u) {
    return (u & 0x80000000u) ? ~u : (u | 0x80000000u);
}
__device__ __forceinline__ unsigned int ford_inv(unsigned int o) {
    return (o & 0x80000000u) ? (o & 0x7fffffffu) : ~o;
}

// BEST-KNOWN (R7, 155.8 µs total; R8's higher-occupancy variant regressed —
// occupancy is not the limiter; the platform streaming wall ~3.25 TB/s
// effective is, per the R5 pure-read probe at 44 µs).
// One 512-thread block per map. ONE HBM sweep (guaranteed by explicit LDS
// staging — R4 proved the compiler reloads "register-kept" data): burst all
// 8 float4/thread, stage to LDS + max-scan in the same pass. One barrier
// (key exchange only). Masked sum re-reads each thread's OWN staged LDS
// values (no 2nd barrier; 2-way LDS aliasing is free), v_sqrt + predicated
// fmaf. 66 KB LDS -> 2 blocks/CU; co-resident block's load burst hides this
// block's reduce/sum tail.
__global__ __launch_bounds__(NTH, 4) void hm_stats(const float* __restrict__ outp,
                                                   const float* __restrict__ tgtp,
                                                   float* __restrict__ d)
{
    __shared__ float hm[HW];                       // 64 KB
    __shared__ unsigned long long rk[NWAVE];
    __shared__ float rs[NWAVE], rc[NWAVE];

    const int m = blockIdx.x;                      // [0, NMAP)
    const int t = threadIdx.x;
    const float* __restrict__ src = (m < BJ)
        ? (outp + (size_t)m * HW)
        : (tgtp + (size_t)(m - BJ) * HW);
    const float4* __restrict__ s4 = (const float4*)src;
    float4* hm4 = (float4*)hm;

    // ---- single load burst (8 float4 outstanding), then stage + 4-chain scan
    float4 v[F4PT];
#pragma unroll
    for (int k = 0; k < F4PT; ++k) v[k] = s4[t + k * NTH];

    float mx0 = -INFINITY, mx1 = -INFINITY, mx2 = -INFINITY, mx3 = -INFINITY;
    int   ix0 = 0, ix1 = 1, ix2 = 2, ix3 = 3;
#pragma unroll
    for (int k = 0; k < F4PT; ++k) {               // per-thread idx grows with k -> '>' keeps first
        hm4[t + k * NTH] = v[k];
        const int base = (t + k * NTH) << 2;
        if (v[k].x > mx0) { mx0 = v[k].x; ix0 = base;     }
        if (v[k].y > mx1) { mx1 = v[k].y; ix1 = base + 1; }
        if (v[k].z > mx2) { mx2 = v[k].z; ix2 = base + 2; }
        if (v[k].w > mx3) { mx3 = v[k].w; ix3 = base + 3; }
    }

    // merge 4 chains via u64 keys: (ord(val)<<32)|~idx — max = (max val, min idx)
    unsigned long long k0 = ((unsigned long long)ford(__float_as_uint(mx0)) << 32) | (unsigned int)~ix0;
    unsigned long long k1 = ((unsigned long long)ford(__float_as_uint(mx1)) << 32) | (unsigned int)~ix1;
    unsigned long long k2 = ((unsigned long long)ford(__float_as_uint(mx2)) << 32) | (unsigned int)~ix2;
    unsigned long long k3 = ((unsigned long long)ford(__float_as_uint(mx3)) << 32) | (unsigned int)~ix3;
    unsigned long long key = k0 > k1 ? k0 : k1;
    key = k2 > key ? k2 : key;
    key = k3 > key ? k3 : key;
#pragma unroll
    for (int off = 32; off >= 1; off >>= 1) {
        const unsigned long long ok = __shfl_xor(key, off, 64);
        key = (ok > key) ? ok : key;
    }
    const int wave = t >> 6, lane = t & 63;
    if (lane == 0) rk[wave] = key;
    __syncthreads();                               // the ONLY data barrier
    unsigned long long bkey = rk[0];
#pragma unroll
    for (int w = 1; w < NWAVE; ++w) bkey = (rk[w] > bkey) ? rk[w] : bkey;

    const float maxv = __uint_as_float(ford_inv((unsigned int)(bkey >> 32)));
    const int   midx = (int)~(unsigned int)(bkey & 0xffffffffu);
    const float ym  = (float)(midx >> 7);          // reference: idx // H (H=128 stride)
    const float xm  = (float)(midx & 127);
    const float thv = maxv * 0.5f;

    // ---- masked distance sum from own staged LDS values (no barrier needed)
    float s = 0.0f, c = 0.0f;
#pragma unroll
    for (int k = 0; k < F4PT; ++k) {
        const float4 w = hm4[t + k * NTH];
        const int g4 = t + k * NTH;
        const float dy  = (float)(g4 >> 5) - ym;   // all 4 elems share a row
        const float dy2 = dy * dy;
        const float cb  = (float)((g4 << 2) & 127) - xm;
        {
            const float dx = cb;        const float ds = __builtin_amdgcn_sqrtf(fmaf(dx, dx, dy2));
            const float mk = (w.x > thv) ? 1.0f : 0.0f;  s = fmaf(mk, ds, s);  c += mk;
        }
        {
            const float dx = cb + 1.0f; const float ds = __builtin_amdgcn_sqrtf(fmaf(dx, dx, dy2));
            const float mk = (w.y > thv) ? 1.0f : 0.0f;  s = fmaf(mk, ds, s);  c += mk;
        }
        {
            const float dx = cb + 2.0f; const float ds = __builtin_amdgcn_sqrtf(fmaf(dx, dx, dy2));
            const float mk = (w.z > thv) ? 1.0f : 0.0f;  s = fmaf(mk, ds, s);  c += mk;
        }
        {
            const float dx = cb + 3.0f; const float ds = __builtin_amdgcn_sqrtf(fmaf(dx, dx, dy2));
            const float mk = (w.w > thv) ? 1.0f : 0.0f;  s = fmaf(mk, ds, s);  c += mk;
        }
    }

#pragma unroll
    for (int off = 32; off >= 1; off >>= 1) {
        s += __shfl_xor(s, off, 64);
        c += __shfl_xor(c, off, 64);
    }
    if (lane == 0) { rs[wave] = s; rc[wave] = c; }
    __syncthreads();
    if (t == 0) {
#pragma unroll
        for (int w = 1; w < NWAVE; ++w) { s += rs[w]; c += rc[w]; }
        const float mean = s / fmaxf(c, 1.0f);
        const float dd   = (c > 0.0f) ? (mean / 181.02f) : 1.0f;   // MAX_DIST
        d[m] = (maxv > 0.0f) ? dd : 0.0f;
    }
}

// Single-block final reduction: sum |gt - pred| / J / B
__global__ __launch_bounds__(256) void finalize(const float* __restrict__ d,
                                                float* __restrict__ out)
{
    __shared__ float rs[4];
    const int t = threadIdx.x;
    float acc = 0.0f;
    for (int i = t; i < BJ; i += 256)
        acc += fabsf(d[BJ + i] - d[i]);
#pragma unroll
    for (int off = 32; off >= 1; off >>= 1)
        acc += __shfl_down(acc, off, 64);
    const int wave = t >> 6, lane = t & 63;
    if (lane == 0) rs[wave] = acc;
    __syncthreads();
    if (t == 0) {
        acc = rs[0] + rs[1] + rs[2] + rs[3];
        out[0] = acc / 17.0f / 64.0f;              // / J / B, reference order
    }
}

extern "C" void kernel_launch(void* const* d_in, const int* in_sizes, int n_in,
                              void* d_out, int out_size, void* d_ws, size_t ws_size,
                              hipStream_t stream) {
    const float* outp = (const float*)d_in[0];     // [64,17,128,128] f32
    const float* tgtp = (const float*)d_in[1];
    float* d = (float*)d_ws;                       // NMAP floats

    hm_stats<<<dim3(NMAP), dim3(NTH), 0, stream>>>(outp, tgtp, d);
    finalize<<<dim3(1),    dim3(256), 0, stream>>>(d, (float*)d_out);
}